// Round 1
// baseline (2600.556 us; speedup 1.0000x reference)
//
#include <hip/hip_runtime.h>
#include <hip/hip_bf16.h>

#define EE 160000
#define NNODES 10000

using bf16 = __hip_bfloat16;

__device__ __forceinline__ float silu_f(float x) { return x / (1.0f + __expf(-x)); }
__device__ __forceinline__ float b2f(bf16 v) { return __bfloat162float(v); }
__device__ __forceinline__ bf16 f2b(float v) { return __float2bfloat16(v); }

// constants
// 1/(16*sqrt(8)), 0.5/sqrt(8), 1/sqrt(8)
#define INV_AVGN_SQM 0.02209708691207961f
#define HALF_INV_SQM 0.17677669529663687f
#define INV_SQM      0.35355339059327373f

// ---------------------------------------------------------------------------
// Kernel A: two-body MLP (16->128->128->128), cutoff, env-MLP (128->48),
// write latents (bf16, transposed), w_init, eaT, cut; atomic-scatter env0.
// One thread = one edge. h staged in a private LDS column (bf16).
// Weights are indexed wave-uniformly -> compiler emits s_load.
// ---------------------------------------------------------------------------
__global__ __launch_bounds__(256, 2) void kA(
    const float* __restrict__ ea, const float* __restrict__ eemb,
    const float* __restrict__ nat, const float* __restrict__ elen,
    const float* __restrict__ w0, const float* __restrict__ w1,
    const float* __restrict__ w2, const float* __restrict__ wm0,
    const int* __restrict__ eidx,
    bf16* __restrict__ latfT, bf16* __restrict__ winiT, bf16* __restrict__ eaT,
    float* __restrict__ cutb, float* __restrict__ env0)
{
    __shared__ bf16 hb[128 * 256];  // 64 KB: per-thread private column
    const int tid = threadIdx.x;
    const int e = blockIdx.x * 256 + tid;
    const int ctr = eidx[e];
    const int ngb = eidx[EE + e];

    float tin[16];
#pragma unroll
    for (int k = 0; k < 4; k++) tin[k] = nat[ctr * 4 + k];
#pragma unroll
    for (int k = 0; k < 4; k++) tin[4 + k] = nat[ngb * 4 + k];
#pragma unroll
    for (int k = 0; k < 8; k++) tin[8 + k] = eemb[e * 8 + k];

    // polynomial cutoff p=6: 1 - 28 x^6 + 48 x^7 - 21 x^8
    const float x = elen[e];
    const float x2 = x * x, x4 = x2 * x2, x6 = x4 * x2, x7 = x6 * x, x8 = x7 * x;
    float cutv = 1.0f - 28.0f * x6 + 48.0f * x7 - 21.0f * x8;
    cutv = (x < 1.0f) ? cutv : 0.0f;
    cutb[e] = cutv;

    // stage 0: h0 = silu(tin @ w0)  [16 -> 128]
    for (int jc = 0; jc < 4; jc++) {
        float acc0[32];
#pragma unroll
        for (int j = 0; j < 32; j++) acc0[j] = 0.0f;
#pragma unroll
        for (int k = 0; k < 16; k++) {
            const float v = tin[k];
#pragma unroll
            for (int j = 0; j < 32; j++)
                acc0[j] = fmaf(v, w0[k * 128 + jc * 32 + j], acc0[j]);
        }
#pragma unroll
        for (int j = 0; j < 32; j++)
            hb[(jc * 32 + j) * 256 + tid] = f2b(silu_f(acc0[j]));
    }

    // stage 1: h1 = silu(h0 @ w1)  [128 -> 128]
    float acc[128];
#pragma unroll
    for (int j = 0; j < 128; j++) acc[j] = 0.0f;
    for (int k = 0; k < 128; k++) {
        const float v = b2f(hb[k * 256 + tid]);
#pragma unroll
        for (int j = 0; j < 128; j++) acc[j] = fmaf(v, w1[k * 128 + j], acc[j]);
    }
#pragma unroll
    for (int j = 0; j < 128; j++) hb[j * 256 + tid] = f2b(silu_f(acc[j]));

    // stage 2: latents = (h1 @ w2) * cut  [128 -> 128]
#pragma unroll
    for (int j = 0; j < 128; j++) acc[j] = 0.0f;
    for (int k = 0; k < 128; k++) {
        const float v = b2f(hb[k * 256 + tid]);
#pragma unroll
        for (int j = 0; j < 128; j++) acc[j] = fmaf(v, w2[k * 128 + j], acc[j]);
    }

    // stage 3: ew = latents @ env_mlp_w0 [128 -> 48]; store latents (bf16 T)
    float ewv[48];
#pragma unroll
    for (int c = 0; c < 48; c++) ewv[c] = 0.0f;
#pragma unroll
    for (int j = 0; j < 128; j++) {
        const float lv = acc[j] * cutv;
        latfT[j * EE + e] = f2b(lv);
#pragma unroll
        for (int c = 0; c < 48; c++) ewv[c] = fmaf(lv, wm0[j * 48 + c], ewv[c]);
    }

    // w_init -> winiT [(i*8+u)][E]
#pragma unroll
    for (int i = 0; i < 3; i++)
#pragma unroll
        for (int u = 0; u < 8; u++)
            winiT[(i * 8 + u) * EE + e] = f2b(ewv[u * 3 + i]);

    // edge_attrs: keep original f32 for scatter, also store bf16 transposed
    float eav[9];
#pragma unroll
    for (int d = 0; d < 9; d++) {
        eav[d] = ea[e * 9 + d];
        eaT[d * EE + e] = f2b(eav[d]);
    }

    // scatter env0 += weight_edges(w_cur): f[u,d] = w_cur[u, ir(d)] * ea[d]
#pragma unroll
    for (int u = 0; u < 8; u++) {
        float* dst = env0 + (ctr * 8 + u) * 9;
        const float a0 = ewv[24 + u * 3 + 0];
        const float a1 = ewv[24 + u * 3 + 1];
        const float a2 = ewv[24 + u * 3 + 2];
        atomicAdd(dst + 0, a0 * eav[0]);
        atomicAdd(dst + 1, a1 * eav[1]);
        atomicAdd(dst + 2, a1 * eav[2]);
        atomicAdd(dst + 3, a1 * eav[3]);
        atomicAdd(dst + 4, a2 * eav[4]);
        atomicAdd(dst + 5, a2 * eav[5]);
        atomicAdd(dst + 6, a2 * eav[6]);
        atomicAdd(dst + 7, a2 * eav[7]);
        atomicAdd(dst + 8, a2 * eav[8]);
    }
}

// ---------------------------------------------------------------------------
// Env transform (in place): env_c[n,u,d] = (1/(16*sqrt(8))) * sum_v Wl[ir(d),u,v]*env[n,v,d]
// One thread per (n,d). Threads own disjoint (n,*,d) address sets -> safe.
// ---------------------------------------------------------------------------
__global__ void kEnv(const float* __restrict__ wl, float* __restrict__ env)
{
    const int t = blockIdx.x * 256 + threadIdx.x;
    if (t >= NNODES * 9) return;
    const int n = t / 9;
    const int d = t - n * 9;
    const int ir = (d == 0) ? 0 : ((d < 4) ? 1 : 2);
    float v[8];
#pragma unroll
    for (int q = 0; q < 8; q++) v[q] = env[(n * 8 + q) * 9 + d];
    float o[8];
#pragma unroll
    for (int u = 0; u < 8; u++) {
        float s = 0.0f;
#pragma unroll
        for (int q = 0; q < 8; q++) s = fmaf(wl[ir * 64 + u * 8 + q], v[q], s);
        o[u] = s * INV_AVGN_SQM;
    }
#pragma unroll
    for (int u = 0; u < 8; u++) env[(n * 8 + u) * 9 + d] = o[u];
}

// ---------------------------------------------------------------------------
// C1: layer-0 interact + invariants.
// features0[u,d] = w_init[u,ir(d)]*ea[d]; new_f = f*ec[:, :1] + ec*f[:, :1]
// writes newfT [(d*8+u)][E] and invariants into latfT rows 128..151
// ---------------------------------------------------------------------------
__global__ __launch_bounds__(256) void kC1(
    const bf16* __restrict__ winiT, const bf16* __restrict__ eaT,
    const float* __restrict__ envc, const int* __restrict__ eidx,
    bf16* __restrict__ newfT, bf16* __restrict__ latfT)
{
    const int e = blockIdx.x * 256 + threadIdx.x;
    const int ctr = eidx[e];
    float eav[9];
#pragma unroll
    for (int d = 0; d < 9; d++) eav[d] = b2f(eaT[d * EE + e]);
    float wini[24];  // [i*8+u]
#pragma unroll
    for (int q = 0; q < 24; q++) wini[q] = b2f(winiT[q * EE + e]);
    const float* ec = envc + ctr * 72;
#pragma unroll
    for (int u = 0; u < 8; u++) {
        float f[9];
#pragma unroll
        for (int d = 0; d < 9; d++) {
            const int ir = (d == 0) ? 0 : ((d < 4) ? 1 : 2);
            f[d] = wini[ir * 8 + u] * eav[d];
        }
        const float ecu0 = ec[u * 9 + 0];
        const float fu0 = f[0];
        float nf[9];
#pragma unroll
        for (int d = 0; d < 9; d++) nf[d] = f[d] * ecu0 + ec[u * 9 + d] * fu0;
#pragma unroll
        for (int d = 0; d < 9; d++) newfT[(d * 8 + u) * EE + e] = f2b(nf[d]);
        const float s0 = nf[0] * nf[0] + 1e-8f;
        const float s1 = nf[1] * nf[1] + nf[2] * nf[2] + nf[3] * nf[3] + 1e-8f;
        const float s2 = nf[4] * nf[4] + nf[5] * nf[5] + nf[6] * nf[6] +
                         nf[7] * nf[7] + nf[8] * nf[8] + 1e-8f;
        latfT[(128 + u * 3 + 0) * EE + e] = f2b(sqrtf(s0));
        latfT[(128 + u * 3 + 1) * EE + e] = f2b(sqrtf(s1));
        latfT[(128 + u * 3 + 2) * EE + e] = f2b(sqrtf(s2));
    }
}

// ---------------------------------------------------------------------------
// C2: features1 = 0.5*peL(latf@l2fold0, feat0) + 0.5*peL(latf@l2fnew0, newf0)
// blockIdx.y = irrep. acc over W_old[i]/W_new[i] (64+64 regs), stream latf.
// ---------------------------------------------------------------------------
__global__ __launch_bounds__(256, 2) void kC2(
    const bf16* __restrict__ latfT, const bf16* __restrict__ winiT,
    const bf16* __restrict__ eaT, const bf16* __restrict__ newfT,
    const float* __restrict__ l2fo, const float* __restrict__ l2fn,
    bf16* __restrict__ feat1T)
{
    const int e = blockIdx.x * 256 + threadIdx.x;
    const int ir = blockIdx.y;
    const int d0 = (ir == 0) ? 0 : ((ir == 1) ? 1 : 4);
    const int nd = (ir == 0) ? 1 : ((ir == 1) ? 3 : 5);
    float accO[64], accN[64];
#pragma unroll
    for (int q = 0; q < 64; q++) { accO[q] = 0.0f; accN[q] = 0.0f; }
    for (int t = 0; t < 152; t++) {
        const float lf = b2f(latfT[t * EE + e]);
        const float* wo = l2fo + t * 192 + ir * 64;
        const float* wn = l2fn + t * 192 + ir * 64;
#pragma unroll
        for (int q = 0; q < 64; q++) {
            accO[q] = fmaf(lf, wo[q], accO[q]);
            accN[q] = fmaf(lf, wn[q], accN[q]);
        }
    }
    float wv[8];
#pragma unroll
    for (int v = 0; v < 8; v++) wv[v] = b2f(winiT[(ir * 8 + v) * EE + e]);
    for (int dd = 0; dd < nd; dd++) {
        const int d = d0 + dd;
        const float ead = b2f(eaT[d * EE + e]);
        float nf[8];
#pragma unroll
        for (int v = 0; v < 8; v++) nf[v] = b2f(newfT[(d * 8 + v) * EE + e]);
#pragma unroll
        for (int u = 0; u < 8; u++) {
            float s = 0.0f;
#pragma unroll
            for (int v = 0; v < 8; v++)
                s += accO[u * 8 + v] * (wv[v] * ead) + accN[u * 8 + v] * nf[v];
            feat1T[(d * 8 + u) * EE + e] = f2b(s * HALF_INV_SQM);
        }
    }
}

// ---------------------------------------------------------------------------
// C3: lat_new = silu(latf @ latent_w)*cut; latents1 = 0.5 lat0 + 0.5 lat_new
// (in place, own column); w_cur1 = latents1 @ env_mlp_w1; scatter env1.
// ---------------------------------------------------------------------------
__global__ __launch_bounds__(256, 2) void kC3(
    bf16* __restrict__ latfT, const float* __restrict__ latw,
    const float* __restrict__ wm1, const bf16* __restrict__ eaT,
    const float* __restrict__ cutb, const int* __restrict__ eidx,
    float* __restrict__ env1)
{
    const int e = blockIdx.x * 256 + threadIdx.x;
    float acc[128];
#pragma unroll
    for (int j = 0; j < 128; j++) acc[j] = 0.0f;
    for (int t = 0; t < 152; t++) {
        const float lf = b2f(latfT[t * EE + e]);
#pragma unroll
        for (int j = 0; j < 128; j++) acc[j] = fmaf(lf, latw[t * 128 + j], acc[j]);
    }
    const float cutv = cutb[e];
    float wc[24];
#pragma unroll
    for (int c = 0; c < 24; c++) wc[c] = 0.0f;
#pragma unroll
    for (int j = 0; j < 128; j++) {
        const float oldv = b2f(latfT[j * EE + e]);
        const float l1 = 0.5f * oldv + 0.5f * silu_f(acc[j]) * cutv;
        latfT[j * EE + e] = f2b(l1);
#pragma unroll
        for (int c = 0; c < 24; c++) wc[c] = fmaf(l1, wm1[j * 24 + c], wc[c]);
    }
    const int ctr = eidx[e];
    float eav[9];
#pragma unroll
    for (int d = 0; d < 9; d++) eav[d] = b2f(eaT[d * EE + e]);
#pragma unroll
    for (int u = 0; u < 8; u++) {
        float* dst = env1 + (ctr * 8 + u) * 9;
        const float a0 = wc[u * 3 + 0];
        const float a1 = wc[u * 3 + 1];
        const float a2 = wc[u * 3 + 2];
        atomicAdd(dst + 0, a0 * eav[0]);
        atomicAdd(dst + 1, a1 * eav[1]);
        atomicAdd(dst + 2, a1 * eav[2]);
        atomicAdd(dst + 3, a1 * eav[3]);
        atomicAdd(dst + 4, a2 * eav[4]);
        atomicAdd(dst + 5, a2 * eav[5]);
        atomicAdd(dst + 6, a2 * eav[6]);
        atomicAdd(dst + 7, a2 * eav[7]);
        atomicAdd(dst + 8, a2 * eav[8]);
    }
}

// ---------------------------------------------------------------------------
// E1: layer-1 interact + invariants (features from feat1T).
// ---------------------------------------------------------------------------
__global__ __launch_bounds__(256) void kE1(
    const bf16* __restrict__ feat1T, const float* __restrict__ envc,
    const int* __restrict__ eidx, bf16* __restrict__ newfT,
    bf16* __restrict__ latfT)
{
    const int e = blockIdx.x * 256 + threadIdx.x;
    const int ctr = eidx[e];
    const float* ec = envc + ctr * 72;
#pragma unroll
    for (int u = 0; u < 8; u++) {
        float f[9];
#pragma unroll
        for (int d = 0; d < 9; d++) f[d] = b2f(feat1T[(d * 8 + u) * EE + e]);
        const float ecu0 = ec[u * 9 + 0];
        const float fu0 = f[0];
        float nf[9];
#pragma unroll
        for (int d = 0; d < 9; d++) nf[d] = f[d] * ecu0 + ec[u * 9 + d] * fu0;
#pragma unroll
        for (int d = 0; d < 9; d++) newfT[(d * 8 + u) * EE + e] = f2b(nf[d]);
        const float s0 = nf[0] * nf[0] + 1e-8f;
        const float s1 = nf[1] * nf[1] + nf[2] * nf[2] + nf[3] * nf[3] + 1e-8f;
        const float s2 = nf[4] * nf[4] + nf[5] * nf[5] + nf[6] * nf[6] +
                         nf[7] * nf[7] + nf[8] * nf[8] + 1e-8f;
        latfT[(128 + u * 3 + 0) * EE + e] = f2b(sqrtf(s0));
        latfT[(128 + u * 3 + 1) * EE + e] = f2b(sqrtf(s1));
        latfT[(128 + u * 3 + 2) * EE + e] = f2b(sqrtf(s2));
    }
}

// ---------------------------------------------------------------------------
// E2: only irrep-1 of layer-1 pe_linear is needed (output takes comps 1:4).
// acc: W_old[1] (64) + W_new[1] (64) + wfin (8); stream latf once.
// ---------------------------------------------------------------------------
__global__ __launch_bounds__(256, 2) void kE2(
    const bf16* __restrict__ latfT, const bf16* __restrict__ feat1T,
    const bf16* __restrict__ newfT,
    const float* __restrict__ l2fo, const float* __restrict__ l2fn,
    const float* __restrict__ finw, float* __restrict__ outp)
{
    const int e = blockIdx.x * 256 + threadIdx.x;
    float accO[64], accN[64], wfin[8];
#pragma unroll
    for (int q = 0; q < 64; q++) { accO[q] = 0.0f; accN[q] = 0.0f; }
#pragma unroll
    for (int m = 0; m < 8; m++) wfin[m] = 0.0f;
    for (int t = 0; t < 152; t++) {
        const float lf = b2f(latfT[t * EE + e]);
        const float* wo = l2fo + t * 192 + 64;
        const float* wn = l2fn + t * 192 + 64;
#pragma unroll
        for (int q = 0; q < 64; q++) {
            accO[q] = fmaf(lf, wo[q], accO[q]);
            accN[q] = fmaf(lf, wn[q], accN[q]);
        }
        const float* fw = finw + t * 8;
#pragma unroll
        for (int m = 0; m < 8; m++) wfin[m] = fmaf(lf, fw[m], wfin[m]);
    }
#pragma unroll
    for (int dd = 0; dd < 3; dd++) {
        const int d = 1 + dd;
        float f1[8], nf[8];
#pragma unroll
        for (int v = 0; v < 8; v++) {
            f1[v] = b2f(feat1T[(d * 8 + v) * EE + e]);
            nf[v] = b2f(newfT[(d * 8 + v) * EE + e]);
        }
        float od = 0.0f;
#pragma unroll
        for (int u = 0; u < 8; u++) {
            float s = 0.0f;
#pragma unroll
            for (int v = 0; v < 8; v++)
                s += accO[u * 8 + v] * f1[v] + accN[u * 8 + v] * nf[v];
            od = fmaf(wfin[u], s * HALF_INV_SQM, od);
        }
        outp[e * 3 + dd] = od * INV_SQM;
    }
}

// ---------------------------------------------------------------------------
extern "C" void kernel_launch(void* const* d_in, const int* in_sizes, int n_in,
                              void* d_out, int out_size, void* d_ws, size_t ws_size,
                              hipStream_t stream)
{
    const float* ea   = (const float*)d_in[0];   // edge_attrs [E,9]
    const float* eemb = (const float*)d_in[1];   // edge_embedding [E,8]
    const float* nat  = (const float*)d_in[2];   // node_attrs [N,4]
    const float* elen = (const float*)d_in[3];   // edge_lengths [E]
    const float* w0   = (const float*)d_in[4];   // tb_w0 [16,128]
    const float* w1   = (const float*)d_in[5];   // tb_w1 [128,128]
    const float* w2   = (const float*)d_in[6];   // tb_w2 [128,128]
    const float* wm0  = (const float*)d_in[7];   // env_mlp_w0 [128,48]
    const float* wm1  = (const float*)d_in[8];   // env_mlp_w1 [128,24]
    const float* envl = (const float*)d_in[9];   // env_linear_w [2,3,8,8]
    const float* latw = (const float*)d_in[10];  // latent_w [152,128]
    const float* l2fn = (const float*)d_in[11];  // lat2feat_w [2,152,192]
    const float* l2fo = (const float*)d_in[12];  // lat2featold_w [2,152,192]
    const float* finw = (const float*)d_in[13];  // final_w [152,8]
    const int*   eidx = (const int*)d_in[14];    // edge_index [2,E]

    char* ws = (char*)d_ws;
    bf16*  latfT  = (bf16*)(ws + 0);            // [152][E] rows 0..127 latents, 128..151 invariants
    bf16*  newfT  = (bf16*)(ws + 48640000);     // [9*8][E]  new_f (d-major)
    bf16*  feat1T = (bf16*)(ws + 71680000);     // [9*8][E]  features after layer 0
    bf16*  winiT  = (bf16*)(ws + 94720000);     // [3*8][E]  w_init (i-major)
    bf16*  eaT    = (bf16*)(ws + 102400000);    // [9][E]
    float* cutb   = (float*)(ws + 105280000);   // [E]
    float* env0   = (float*)(ws + 105920000);   // [N*8*9]
    float* env1   = (float*)(ws + 108800000);   // [N*8*9]

    // zero both env accumulators (contiguous)
    hipMemsetAsync(env0, 0, 2u * 720000u * 4u, stream);

    kA<<<625, 256, 0, stream>>>(ea, eemb, nat, elen, w0, w1, w2, wm0, eidx,
                                latfT, winiT, eaT, cutb, env0);
    kEnv<<<352, 256, 0, stream>>>(envl + 0, env0);
    kC1<<<625, 256, 0, stream>>>(winiT, eaT, env0, eidx, newfT, latfT);
    kC2<<<dim3(625, 3), 256, 0, stream>>>(latfT, winiT, eaT, newfT,
                                          l2fo + 0, l2fn + 0, feat1T);
    kC3<<<625, 256, 0, stream>>>(latfT, latw, wm1, eaT, cutb, eidx, env1);
    kEnv<<<352, 256, 0, stream>>>(envl + 192, env1);
    kE1<<<625, 256, 0, stream>>>(feat1T, env1, eidx, newfT, latfT);
    kE2<<<625, 256, 0, stream>>>(latfT, feat1T, newfT,
                                 l2fo + 29184, l2fn + 29184, finw,
                                 (float*)d_out);
}